// Round 7
// baseline (111.461 us; speedup 1.0000x reference)
//
#include <hip/hip_runtime.h>
#include <math.h>

#define RAD 5
#define SIDE 80
#define SLAB 6400      // 80*80
#define VOL 512000     // 80^3
#define NCH 8          // N*K
#define NCLS 4
#define Q 20           // float4/ushort4 columns per 80-elem row
#define TW 40          // K1 tile extent along w (halo 1.25x; 1280 blocks = 5/CU resident)
#define NT 2           // w-tiles per axis (80/40)
#define C1 (SIDE*NT)           // 160 K1 slots per channel
#define NBLK1 (NCH*C1)         // 1280 K1 blocks
#define TBS 22                 // tB row stride in float4
#define NBLK2 1280             // K2 blocks: (c, w, h-half) = 8*80*2, 5/CU exact
#define CPB 160                // K2 blocks per channel
#define SBS 84                 // K2 LDS row stride in floats (21 float4, 336 B)
#define FXS 1048576.0f         // fixed-point scale 2^20 for int64 accumulation

// exp(-t^2/32) for t=-5..5 (unnormalized Gaussian, symmetric)
__constant__ float GW[11] = {
    0.45783336177161427f, 0.6065306597126334f, 0.7548396019890073f,
    0.8824969025845955f,  0.969233234476344f,  1.0f,
    0.969233234476344f,   0.8824969025845955f, 0.7548396019890073f,
    0.6065306597126334f,  0.45783336177161427f};

// Module-scope scratch. Cross-kernel dataflow: slot stores + kernel boundary.
// R16: K3 fused into K2 via fine-grained int64 atomics (deterministic,
// fence-free — atomics execute at the device coherent point; the R8 "+100 µs"
// measurement was threadfence/L2-writeback patterns, not atomic RMW).
__device__ unsigned short g_bufT[(size_t)NCH * VOL];  // bf16 conv'd labels, [c][w][h][d]
__device__ float2 g_part1[NBLK1];             // {S_ip, S_p} per K1 block
__device__ unsigned long long g_acc[2 * NCH]; // fixed-point num[0..7], den[8..15]
__device__ unsigned g_ctr;                    // K2 completion ticket

__device__ __forceinline__ unsigned short f2bf(float f) {
    unsigned u = __float_as_uint(f);
    u += 0x7FFFu + ((u >> 16) & 1u);          // round-to-nearest-even
    return (unsigned short)(u >> 16);
}
__device__ __forceinline__ float bf2f(unsigned short h) {
    return __uint_as_float((unsigned)h << 16);
}

// K1: per (c, h, w-tile40): d-conv via register window from global,
// fused channel sums, w-conv via LDS gather, transposed bf16 store to g_bufT.
// (R15 phase-A shape: one thread = one (row, 16-output d-group), a[32] from
// 8 guarded b128 loads.) Block 0 additionally re-zeroes the atomic
// accumulators each launch (kernel boundary publishes to K2).
__global__ void __launch_bounds__(256) convdw_sums_kernel(
        const float* __restrict__ labels, const float* __restrict__ img) {
    if (blockIdx.x == 0) {
        if (threadIdx.x < 2 * NCH) g_acc[threadIdx.x] = 0ull;
        if (threadIdx.x == 0) g_ctr = 0u;
    }
    const int tile = blockIdx.x;
    const int c   = tile / C1;
    const int rem = tile % C1;
    const int h   = rem / NT;
    const int w0  = (rem % NT) * TW;
    const int n   = c >> 2;

    __shared__ float4 tB[(TW + 10) * TBS];   // d-conv result rows w0-5..w0+TW+4
    __shared__ float sm[8];

    const float4* labc4 = (const float4*)(labels + ((size_t)c * SIDE + h) * SLAB);
    const float4* imgc4 = (const float4*)(img + ((size_t)n * SIDE + h) * SLAB);

    float sip = 0.f, sp = 0.f;
    if (threadIdx.x < 250) {                 // 50 rows x 5 d-groups, 1 item/thread
        const int r  = threadIdx.x / 5;      // staged row 0..49
        const int qg = threadIdx.x % 5;      // 16-output d-group 0..4
        const int w  = w0 - RAD + r;
        float a[32];                         // labels at d = 16qg-8 .. 16qg+23
        #pragma unroll
        for (int j = 0; j < 32; ++j) a[j] = 0.f;
        if ((unsigned)w < SIDE) {
            const float4* row = labc4 + (size_t)w * Q;
            #pragma unroll
            for (int j = 0; j < 8; ++j) {
                int ss = 4 * qg - 2 + j;
                if (ss >= 0 && ss < Q) {
                    float4 v = row[ss];
                    a[4 * j] = v.x; a[4 * j + 1] = v.y;
                    a[4 * j + 2] = v.z; a[4 * j + 3] = v.w;
                }
            }
            if (r >= RAD && r < RAD + TW) {  // central rows: fused channel sums
                #pragma unroll
                for (int jj = 0; jj < 4; ++jj) {
                    float4 v = imgc4[(size_t)w * Q + 4 * qg + jj];
                    sip += a[8 + 4 * jj] * v.x + a[9 + 4 * jj] * v.y +
                           a[10 + 4 * jj] * v.z + a[11 + 4 * jj] * v.w;
                    sp  += a[8 + 4 * jj] + a[9 + 4 * jj] +
                           a[10 + 4 * jj] + a[11 + 4 * jj];
                }
            }
        }
        // 4 output float4s: output d = 16qg+m at a[m+8]; tap t -> a[m+t+3]
        #pragma unroll
        for (int jj = 0; jj < 4; ++jj) {
            float s0 = 0.f, s1 = 0.f, s2 = 0.f, s3 = 0.f;
            #pragma unroll
            for (int t = 0; t < 11; ++t) {
                float g = GW[t];
                s0 += g * a[4 * jj + t + 3]; s1 += g * a[4 * jj + t + 4];
                s2 += g * a[4 * jj + t + 5]; s3 += g * a[4 * jj + t + 6];
            }
            tB[r * TBS + 4 * qg + jj] = make_float4(s0, s1, s2, s3);
        }
    }
    // block-reduce sums (same barrier covers tB completion + sm visibility)
    #pragma unroll
    for (int off = 32; off > 0; off >>= 1) {
        sip += __shfl_down(sip, off);
        sp  += __shfl_down(sp, off);
    }
    const int lane = threadIdx.x & 63;
    const int wid  = threadIdx.x >> 6;
    if (lane == 0) { sm[wid * 2] = sip; sm[wid * 2 + 1] = sp; }
    __syncthreads();
    if (threadIdx.x == 0)
        g_part1[tile] = make_float2(sm[0] + sm[2] + sm[4] + sm[6],
                                    sm[1] + sm[3] + sm[5] + sm[7]);
    // w-conv (11-tap LDS gather) + transposed bf16 ushort4 store
    ushort4* out4 = (ushort4*)g_bufT + ((size_t)c * VOL + (size_t)h * SIDE) / 4;
    for (int i = threadIdx.x; i < TW * Q; i += 256) {
        const int rl = i / Q, q = i - (i / Q) * Q;
        float sx = 0.f, sy = 0.f, sz = 0.f, sw = 0.f;
        #pragma unroll
        for (int t = 0; t < 11; ++t) {
            float g = GW[t];
            float4 v = tB[(rl + t) * TBS + q];
            sx += g * v.x; sy += g * v.y; sz += g * v.z; sw += g * v.w;
        }
        ushort4 o;
        o.x = f2bf(sx); o.y = f2bf(sy); o.z = f2bf(sz); o.w = f2bf(sw);
        out4[(size_t)(w0 + rl) * (SLAB / 4) + q] = o;
    }
}

// K2 (R14 winner body): block = (c, w, h-half). Stage contiguous bf16 chunk
// -> f32 LDS once, h-conv from LDS, fused weights + dot.
// R16 epilogue: per-block {num,den} quantized to int64 and atomicAdd'ed into
// g_acc (deterministic integer accumulation at the coherent point); ticket
// counter elects the last block to compute and store the loss. K3 deleted.
__global__ void __launch_bounds__(256) convh_dot_kernel(
        const float* __restrict__ labels, const float* __restrict__ img,
        float* __restrict__ out) {
    const int c   = blockIdx.x / CPB;
    const int rw  = blockIdx.x % CPB;
    const int w   = rw >> 1;
    const int hh0 = (rw & 1) * 40;
    const int n   = c >> 2;

    __shared__ float sB[50 * SBS];   // f32 window rows hh0-5..hh0+44
    __shared__ float sm[8];
    const int lane = threadIdx.x & 63;
    const int wid  = threadIdx.x >> 6;

    // oldest loads: mean partials (1 per thread, C1=160)
    float a = 0.f, b = 0.f;
    if (threadIdx.x < C1) {
        float2 p = g_part1[c * C1 + threadIdx.x];
        a = p.x; b = p.y;
    }

    // stage: contiguous bf16 chunk -> f32 LDS rows (zero-pad OOB halo)
    const ushort4* src = (const ushort4*)g_bufT + ((size_t)c * VOL + (size_t)w * SLAB) / 4;
    for (int i = threadIdx.x; i < 50 * Q; i += 256) {
        const int row = i / Q, s = i - (i / Q) * Q;
        const int hh = hh0 - RAD + row;
        float4 v = make_float4(0.f, 0.f, 0.f, 0.f);
        if ((unsigned)hh < SIDE) {
            ushort4 u = src[hh * Q + s];
            v = make_float4(bf2f(u.x), bf2f(u.y), bf2f(u.z), bf2f(u.w));
        }
        *(float4*)&sB[row * SBS + s * 4] = v;
    }

    // mean reduce (only needs the g_part1 loads)
    #pragma unroll
    for (int off = 32; off > 0; off >>= 1) {
        a += __shfl_down(a, off);
        b += __shfl_down(b, off);
    }
    if (lane == 0) { sm[wid * 2] = a; sm[wid * 2 + 1] = b; }
    __syncthreads();   // covers sB staging + sm visibility
    const float mean = (sm[0] + sm[2] + sm[4] + sm[6]) /
                       (sm[1] + sm[3] + sm[5] + sm[7] + 5.12f);   // VOL*EPS_MEAN

    // h-conv from LDS + fused weights + dot.  800 items = (40 h) x (20 q)
    const float4* labp4 = (const float4*)labels + (size_t)c * (VOL / 4);
    const float4* imgp4 = (const float4*)img + (size_t)n * (VOL / 4);
    float num = 0.f, den = 0.f;
    for (int i = threadIdx.x; i < TW * Q; i += 256) {
        const int hl = i / Q, q = i - (i / Q) * Q;
        const int h  = hh0 + hl;
        float sx = 0.f, sy = 0.f, sz = 0.f, sw = 0.f;
        #pragma unroll
        for (int t = 0; t < 11; ++t) {
            float g = GW[t];
            float4 v = *(const float4*)&sB[(hl + t) * SBS + q * 4];
            sx += g * v.x; sy += g * v.y; sz += g * v.z; sw += g * v.w;
        }
        const int li = h * (SLAB / 4) + w * Q + q;
        float4 l = labp4[li];
        float4 v = imgp4[li];
        float d0 = v.x - mean, d1 = v.y - mean, d2 = v.z - mean, d3 = v.w - mean;
        float q0 = d0 * d0, q1 = d1 * d1, q2 = d2 * d2, q3 = d3 * d3;
        float e0 = __expf(-q0 * q0), e1 = __expf(-q1 * q1);
        float e2 = __expf(-q2 * q2), e3 = __expf(-q3 * q3);
        num += sx * l.x * e0 + sy * l.y * e1 + sz * l.z * e2 + sw * l.w * e3;
        den += sx * e0 + sy * e1 + sz * e2 + sw * e3;
    }
    #pragma unroll
    for (int off = 32; off > 0; off >>= 1) {
        num += __shfl_down(num, off);
        den += __shfl_down(den, off);
    }
    __syncthreads();   // all threads done reading sm (mean) before reuse
    if (lane == 0) { sm[wid * 2] = num; sm[wid * 2 + 1] = den; }
    __syncthreads();
    if (threadIdx.x == 0) {
        const float bn = sm[0] + sm[2] + sm[4] + sm[6];
        const float bd = sm[1] + sm[3] + sm[5] + sm[7];
        // nonneg by construction; fixed-point quantize (error ~1e-7 rel)
        unsigned long long qn = (unsigned long long)(long long)rintf(bn * FXS);
        unsigned long long qd = (unsigned long long)(long long)rintf(bd * FXS);
        unsigned long long on = atomicAdd(&g_acc[c], qn);
        unsigned long long od = atomicAdd(&g_acc[NCH + c], qd);
        // consume returns -> value atomics completed at coherent point
        // before the ticket issues (compile-time + vmcnt ordering)
        asm volatile("" :: "v"(on), "v"(od));
        unsigned t = atomicAdd(&g_ctr, 1u);
        if (t == NBLK2 - 1) {                 // last block: finalize loss
            float loss = 0.f;
            #pragma unroll
            for (int k = 0; k < NCLS; ++k) {
                long long n0 = (long long)atomicAdd(&g_acc[k], 0ull);
                long long d0_ = (long long)atomicAdd(&g_acc[NCH + k], 0ull);
                long long n1 = (long long)atomicAdd(&g_acc[NCLS + k], 0ull);
                long long d1_ = (long long)atomicAdd(&g_acc[NCH + NCLS + k], 0ull);
                float r0 = ((float)n0 / FXS) / ((float)d0_ / FXS + 1e-6f);
                float r1 = ((float)n1 / FXS) / ((float)d1_ / FXS + 1e-6f);
                loss += 0.5f * (fabsf(r0) + fabsf(r1));   // mean over N=2, sum K
            }
            out[0] = (float)NCLS - loss;
        }
    }
}

extern "C" void kernel_launch(void* const* d_in, const int* in_sizes, int n_in,
                              void* d_out, int out_size, void* d_ws, size_t ws_size,
                              hipStream_t stream) {
    const float* labels = (const float*)d_in[0];   // (2,4,80,80,80) f32
    const float* img    = (const float*)d_in[1];   // (2,1,80,80,80) f32
    float* out = (float*)d_out;                    // 1 float
    (void)d_ws; (void)ws_size;                     // module-scope scratch

    hipLaunchKernelGGL(convdw_sums_kernel, dim3(NBLK1), dim3(256), 0, stream, labels, img);
    hipLaunchKernelGGL(convh_dot_kernel,   dim3(NBLK2), dim3(256), 0, stream, labels, img, out);
}

// Round 8
// 106.958 us; speedup vs baseline: 1.0421x; 1.0421x over previous
//
#include <hip/hip_runtime.h>
#include <math.h>

#define RAD 5
#define SIDE 80
#define SLAB 6400      // 80*80
#define VOL 512000     // 80^3
#define NCH 8          // N*K
#define NCLS 4
#define Q 20           // float4/ushort4 columns per 80-elem row
#define TW 40          // K1 tile extent along w (halo 1.25x; 1280 blocks = 5/CU resident)
#define NT 2           // w-tiles per axis (80/40)
#define C1 (SIDE*NT)           // 160 K1 slots per channel
#define NBLK1 (NCH*C1)         // 1280 K1 blocks
#define TBS 22                 // tB row stride in float4
#define NBLK2 1280             // K2 blocks: (c, w, h-half) = 8*80*2, 5/CU exact
#define CPB 160                // K2 blocks per channel
#define SBS 84                 // K2 LDS row stride in floats (21 float4, 336 B)

// exp(-t^2/32) for t=-5..5 (unnormalized Gaussian, symmetric)
__constant__ float GW[11] = {
    0.45783336177161427f, 0.6065306597126334f, 0.7548396019890073f,
    0.8824969025845955f,  0.969233234476344f,  1.0f,
    0.969233234476344f,   0.8824969025845955f, 0.7548396019890073f,
    0.6065306597126334f,  0.45783336177161427f};

// Module-scope scratch. Slot-based cross-kernel dataflow ONLY.
// R8/R16 lesson (twice-measured): device-scope atomics/fences cost tens of µs
// at 1000+ block scale on gfx950 — kernel boundaries are the ONLY sync used.
// R12 lesson: residency-critical kernels need LDS small enough for 5 blocks/CU.
__device__ unsigned short g_bufT[(size_t)NCH * VOL];  // bf16 conv'd labels, [c][w][h][d]
__device__ float2 g_part1[NBLK1];             // {S_ip, S_p} per K1 block
__device__ float2 g_part2[NBLK2];             // {num, den} per K2 block

__device__ __forceinline__ unsigned short f2bf(float f) {
    unsigned u = __float_as_uint(f);
    u += 0x7FFFu + ((u >> 16) & 1u);          // round-to-nearest-even
    return (unsigned short)(u >> 16);
}
__device__ __forceinline__ float bf2f(unsigned short h) {
    return __uint_as_float((unsigned)h << 16);
}

// K1: per (c, h, w-tile40): d-conv via register window from global,
// fused channel sums, w-conv via LDS gather, transposed bf16 store to g_bufT.
// (R15 phase-A shape: one thread = one (row, 16-output d-group), a[32] from
// 8 guarded b128 loads. IDEMPOTENT — R17 launches it 3x as a timing probe.)
__global__ void __launch_bounds__(256) convdw_sums_kernel(
        const float* __restrict__ labels, const float* __restrict__ img) {
    const int tile = blockIdx.x;
    const int c   = tile / C1;
    const int rem = tile % C1;
    const int h   = rem / NT;
    const int w0  = (rem % NT) * TW;
    const int n   = c >> 2;

    __shared__ float4 tB[(TW + 10) * TBS];   // d-conv result rows w0-5..w0+TW+4
    __shared__ float sm[8];

    const float4* labc4 = (const float4*)(labels + ((size_t)c * SIDE + h) * SLAB);
    const float4* imgc4 = (const float4*)(img + ((size_t)n * SIDE + h) * SLAB);

    float sip = 0.f, sp = 0.f;
    if (threadIdx.x < 250) {                 // 50 rows x 5 d-groups, 1 item/thread
        const int r  = threadIdx.x / 5;      // staged row 0..49
        const int qg = threadIdx.x % 5;      // 16-output d-group 0..4
        const int w  = w0 - RAD + r;
        float a[32];                         // labels at d = 16qg-8 .. 16qg+23
        #pragma unroll
        for (int j = 0; j < 32; ++j) a[j] = 0.f;
        if ((unsigned)w < SIDE) {
            const float4* row = labc4 + (size_t)w * Q;
            #pragma unroll
            for (int j = 0; j < 8; ++j) {
                int ss = 4 * qg - 2 + j;
                if (ss >= 0 && ss < Q) {
                    float4 v = row[ss];
                    a[4 * j] = v.x; a[4 * j + 1] = v.y;
                    a[4 * j + 2] = v.z; a[4 * j + 3] = v.w;
                }
            }
            if (r >= RAD && r < RAD + TW) {  // central rows: fused channel sums
                #pragma unroll
                for (int jj = 0; jj < 4; ++jj) {
                    float4 v = imgc4[(size_t)w * Q + 4 * qg + jj];
                    sip += a[8 + 4 * jj] * v.x + a[9 + 4 * jj] * v.y +
                           a[10 + 4 * jj] * v.z + a[11 + 4 * jj] * v.w;
                    sp  += a[8 + 4 * jj] + a[9 + 4 * jj] +
                           a[10 + 4 * jj] + a[11 + 4 * jj];
                }
            }
        }
        // 4 output float4s: output d = 16qg+m at a[m+8]; tap t -> a[m+t+3]
        #pragma unroll
        for (int jj = 0; jj < 4; ++jj) {
            float s0 = 0.f, s1 = 0.f, s2 = 0.f, s3 = 0.f;
            #pragma unroll
            for (int t = 0; t < 11; ++t) {
                float g = GW[t];
                s0 += g * a[4 * jj + t + 3]; s1 += g * a[4 * jj + t + 4];
                s2 += g * a[4 * jj + t + 5]; s3 += g * a[4 * jj + t + 6];
            }
            tB[r * TBS + 4 * qg + jj] = make_float4(s0, s1, s2, s3);
        }
    }
    // block-reduce sums (same barrier covers tB completion + sm visibility)
    #pragma unroll
    for (int off = 32; off > 0; off >>= 1) {
        sip += __shfl_down(sip, off);
        sp  += __shfl_down(sp, off);
    }
    const int lane = threadIdx.x & 63;
    const int wid  = threadIdx.x >> 6;
    if (lane == 0) { sm[wid * 2] = sip; sm[wid * 2 + 1] = sp; }
    __syncthreads();
    if (threadIdx.x == 0)
        g_part1[tile] = make_float2(sm[0] + sm[2] + sm[4] + sm[6],
                                    sm[1] + sm[3] + sm[5] + sm[7]);
    // w-conv (11-tap LDS gather) + transposed bf16 ushort4 store
    ushort4* out4 = (ushort4*)g_bufT + ((size_t)c * VOL + (size_t)h * SIDE) / 4;
    for (int i = threadIdx.x; i < TW * Q; i += 256) {
        const int rl = i / Q, q = i - (i / Q) * Q;
        float sx = 0.f, sy = 0.f, sz = 0.f, sw = 0.f;
        #pragma unroll
        for (int t = 0; t < 11; ++t) {
            float g = GW[t];
            float4 v = tB[(rl + t) * TBS + q];
            sx += g * v.x; sy += g * v.y; sz += g * v.z; sw += g * v.w;
        }
        ushort4 o;
        o.x = f2bf(sx); o.y = f2bf(sy); o.z = f2bf(sz); o.w = f2bf(sw);
        out4[(size_t)(w0 + rl) * (SLAB / 4) + q] = o;
    }
}

// K2 (R14 winner, verbatim): block = (c, w, h-half). Stage the contiguous
// g_bufT[c][w][hh0-5..hh0+44][:] chunk (8 KB) into LDS as f32 ONCE
// (coalesced, 1.25x halo vs per-thread 3.5x window redundancy;
// bf16 cvt amortized to staging), h-conv from LDS, fused weights + dot.
// 1280 blocks = 5/CU exact; LDS 16.8 KB -> residency not limiting.
__global__ void __launch_bounds__(256) convh_dot_kernel(
        const float* __restrict__ labels, const float* __restrict__ img) {
    const int c   = blockIdx.x / CPB;
    const int rw  = blockIdx.x % CPB;
    const int w   = rw >> 1;
    const int hh0 = (rw & 1) * 40;
    const int n   = c >> 2;

    __shared__ float sB[50 * SBS];   // f32 window rows hh0-5..hh0+44
    __shared__ float sm[8];
    const int lane = threadIdx.x & 63;
    const int wid  = threadIdx.x >> 6;

    // oldest loads: mean partials (1 per thread, C1=160)
    float a = 0.f, b = 0.f;
    if (threadIdx.x < C1) {
        float2 p = g_part1[c * C1 + threadIdx.x];
        a = p.x; b = p.y;
    }

    // stage: contiguous bf16 chunk -> f32 LDS rows (zero-pad OOB halo)
    const ushort4* src = (const ushort4*)g_bufT + ((size_t)c * VOL + (size_t)w * SLAB) / 4;
    for (int i = threadIdx.x; i < 50 * Q; i += 256) {
        const int row = i / Q, s = i - (i / Q) * Q;
        const int hh = hh0 - RAD + row;
        float4 v = make_float4(0.f, 0.f, 0.f, 0.f);
        if ((unsigned)hh < SIDE) {
            ushort4 u = src[hh * Q + s];
            v = make_float4(bf2f(u.x), bf2f(u.y), bf2f(u.z), bf2f(u.w));
        }
        *(float4*)&sB[row * SBS + s * 4] = v;
    }

    // mean reduce (only needs the g_part1 loads)
    #pragma unroll
    for (int off = 32; off > 0; off >>= 1) {
        a += __shfl_down(a, off);
        b += __shfl_down(b, off);
    }
    if (lane == 0) { sm[wid * 2] = a; sm[wid * 2 + 1] = b; }
    __syncthreads();   // covers sB staging + sm visibility
    const float mean = (sm[0] + sm[2] + sm[4] + sm[6]) /
                       (sm[1] + sm[3] + sm[5] + sm[7] + 5.12f);   // VOL*EPS_MEAN

    // h-conv from LDS + fused weights + dot.  800 items = (40 h) x (20 q)
    const float4* labp4 = (const float4*)labels + (size_t)c * (VOL / 4);
    const float4* imgp4 = (const float4*)img + (size_t)n * (VOL / 4);
    float num = 0.f, den = 0.f;
    for (int i = threadIdx.x; i < TW * Q; i += 256) {
        const int hl = i / Q, q = i - (i / Q) * Q;
        const int h  = hh0 + hl;
        float sx = 0.f, sy = 0.f, sz = 0.f, sw = 0.f;
        #pragma unroll
        for (int t = 0; t < 11; ++t) {
            float g = GW[t];
            float4 v = *(const float4*)&sB[(hl + t) * SBS + q * 4];
            sx += g * v.x; sy += g * v.y; sz += g * v.z; sw += g * v.w;
        }
        const int li = h * (SLAB / 4) + w * Q + q;
        float4 l = labp4[li];
        float4 v = imgp4[li];
        float d0 = v.x - mean, d1 = v.y - mean, d2 = v.z - mean, d3 = v.w - mean;
        float q0 = d0 * d0, q1 = d1 * d1, q2 = d2 * d2, q3 = d3 * d3;
        float e0 = __expf(-q0 * q0), e1 = __expf(-q1 * q1);
        float e2 = __expf(-q2 * q2), e3 = __expf(-q3 * q3);
        num += sx * l.x * e0 + sy * l.y * e1 + sz * l.z * e2 + sw * l.w * e3;
        den += sx * e0 + sy * e1 + sz * e2 + sw * e3;
    }
    #pragma unroll
    for (int off = 32; off > 0; off >>= 1) {
        num += __shfl_down(num, off);
        den += __shfl_down(den, off);
    }
    __syncthreads();   // all threads done reading sm (mean) before reuse
    if (lane == 0) { sm[wid * 2] = num; sm[wid * 2 + 1] = den; }
    __syncthreads();
    if (threadIdx.x == 0)
        g_part2[blockIdx.x] = make_float2(sm[0] + sm[2] + sm[4] + sm[6],
                                          sm[1] + sm[3] + sm[5] + sm[7]);
}

// K3: reduce K2's per-block partials -> per-channel ratio -> loss scalar.
// Wave-parallel over channels (4 waves x 2 ch, 1 barrier). CPB=160.
__global__ void __launch_bounds__(256) final_kernel(float* __restrict__ out) {
    __shared__ float cn[NCH], cd[NCH];
    const int lane = threadIdx.x & 63;
    const int wid  = threadIdx.x >> 6;
    #pragma unroll
    for (int cc = 0; cc < 2; ++cc) {
        const int c = wid * 2 + cc;
        float a = 0.f, b = 0.f;
        for (int t = lane; t < CPB; t += 64) {
            float2 p = g_part2[c * CPB + t];
            a += p.x; b += p.y;
        }
        #pragma unroll
        for (int off = 32; off > 0; off >>= 1) {
            a += __shfl_down(a, off);
            b += __shfl_down(b, off);
        }
        if (lane == 0) { cn[c] = a; cd[c] = b; }
    }
    __syncthreads();
    if (threadIdx.x == 0) {
        float loss = 0.f;
        for (int k = 0; k < NCLS; ++k) {
            float r0 = cn[k]        / (cd[k]        + 1e-6f);
            float r1 = cn[NCLS + k] / (cd[NCLS + k] + 1e-6f);
            loss += 0.5f * (fabsf(r0) + fabsf(r1));   // mean over N=2, sum over K
        }
        out[0] = (float)NCLS - loss;
    }
}

extern "C" void kernel_launch(void* const* d_in, const int* in_sizes, int n_in,
                              void* d_out, int out_size, void* d_ws, size_t ws_size,
                              hipStream_t stream) {
    const float* labels = (const float*)d_in[0];   // (2,4,80,80,80) f32
    const float* img    = (const float*)d_in[1];   // (2,1,80,80,80) f32
    float* out = (float*)d_out;                    // 1 float
    (void)d_ws; (void)ws_size;                     // module-scope scratch

    // R17 MEASUREMENT ROUND: K1 launched 3x (idempotent -> output unchanged).
    // dur = base + 2*(K1+gap); resolves the per-kernel time split that the
    // fill-dominated top-5 profile rows have been masking for 6 rounds.
    hipLaunchKernelGGL(convdw_sums_kernel, dim3(NBLK1), dim3(256), 0, stream, labels, img);
    hipLaunchKernelGGL(convdw_sums_kernel, dim3(NBLK1), dim3(256), 0, stream, labels, img);
    hipLaunchKernelGGL(convdw_sums_kernel, dim3(NBLK1), dim3(256), 0, stream, labels, img);
    hipLaunchKernelGGL(convh_dot_kernel,   dim3(NBLK2), dim3(256), 0, stream, labels, img);
    hipLaunchKernelGGL(final_kernel,       dim3(1),     dim3(256), 0, stream, out);
}

// Round 9
// 104.709 us; speedup vs baseline: 1.0645x; 1.0215x over previous
//
#include <hip/hip_runtime.h>
#include <math.h>

#define RAD 5
#define SIDE 80
#define SLAB 6400      // 80*80
#define VOL 512000     // 80^3
#define NCH 8          // N*K
#define NCLS 4
#define Q 20           // float4/ushort4 columns per 80-elem row
#define TW 40          // K1 tile extent along w (halo 1.25x; 1280 blocks = 5/CU resident)
#define NT 2           // w-tiles per axis (80/40)
#define C1 (SIDE*NT)           // 160 K1 slots per channel
#define NBLK1 (NCH*C1)         // 1280 K1 blocks
#define TBS 22                 // tB row stride in float4
#define NBLK2 1280             // K2 blocks: (c, w, h-half) = 8*80*2, 5/CU exact
#define CPB 160                // K2 blocks per channel
#define SBS 84                 // K2 LDS row stride in floats (21 float4, 336 B)

// exp(-t^2/32) for t=-5..5 (unnormalized Gaussian, symmetric)
__constant__ float GW[11] = {
    0.45783336177161427f, 0.6065306597126334f, 0.7548396019890073f,
    0.8824969025845955f,  0.969233234476344f,  1.0f,
    0.969233234476344f,   0.8824969025845955f, 0.7548396019890073f,
    0.6065306597126334f,  0.45783336177161427f};

// Module-scope scratch. Slot-based cross-kernel dataflow ONLY.
// R8/R16 lesson (twice-measured): device-scope atomics/fences cost tens of µs
// at 1000+ block scale on gfx950 — kernel boundaries are the ONLY sync used.
// R12 lesson: residency-critical kernels need LDS small enough for 5 blocks/CU.
// R17 measurement: K1 + launch gap = 10.5 µs (~1.5x its traffic roofline).
__device__ unsigned short g_bufT[(size_t)NCH * VOL];  // bf16 conv'd labels, [c][w][h][d]
__device__ float2 g_part1[NBLK1];             // {S_ip, S_p} per K1 block
__device__ float2 g_part2[NBLK2];             // {num, den} per K2 block

__device__ __forceinline__ unsigned short f2bf(float f) {
    unsigned u = __float_as_uint(f);
    u += 0x7FFFu + ((u >> 16) & 1u);          // round-to-nearest-even
    return (unsigned short)(u >> 16);
}
__device__ __forceinline__ float bf2f(unsigned short h) {
    return __uint_as_float((unsigned)h << 16);
}

// K1: per (c, h, w-tile40): d-conv via register window from global,
// fused channel sums, w-conv via LDS gather, transposed bf16 store to g_bufT.
// (R15 phase-A shape: one thread = one (row, 16-output d-group), a[32] from
// 8 guarded b128 loads.)
__global__ void __launch_bounds__(256) convdw_sums_kernel(
        const float* __restrict__ labels, const float* __restrict__ img) {
    const int tile = blockIdx.x;
    const int c   = tile / C1;
    const int rem = tile % C1;
    const int h   = rem / NT;
    const int w0  = (rem % NT) * TW;
    const int n   = c >> 2;

    __shared__ float4 tB[(TW + 10) * TBS];   // d-conv result rows w0-5..w0+TW+4
    __shared__ float sm[8];

    const float4* labc4 = (const float4*)(labels + ((size_t)c * SIDE + h) * SLAB);
    const float4* imgc4 = (const float4*)(img + ((size_t)n * SIDE + h) * SLAB);

    float sip = 0.f, sp = 0.f;
    if (threadIdx.x < 250) {                 // 50 rows x 5 d-groups, 1 item/thread
        const int r  = threadIdx.x / 5;      // staged row 0..49
        const int qg = threadIdx.x % 5;      // 16-output d-group 0..4
        const int w  = w0 - RAD + r;
        float a[32];                         // labels at d = 16qg-8 .. 16qg+23
        #pragma unroll
        for (int j = 0; j < 32; ++j) a[j] = 0.f;
        if ((unsigned)w < SIDE) {
            const float4* row = labc4 + (size_t)w * Q;
            #pragma unroll
            for (int j = 0; j < 8; ++j) {
                int ss = 4 * qg - 2 + j;
                if (ss >= 0 && ss < Q) {
                    float4 v = row[ss];
                    a[4 * j] = v.x; a[4 * j + 1] = v.y;
                    a[4 * j + 2] = v.z; a[4 * j + 3] = v.w;
                }
            }
            if (r >= RAD && r < RAD + TW) {  // central rows: fused channel sums
                #pragma unroll
                for (int jj = 0; jj < 4; ++jj) {
                    float4 v = imgc4[(size_t)w * Q + 4 * qg + jj];
                    sip += a[8 + 4 * jj] * v.x + a[9 + 4 * jj] * v.y +
                           a[10 + 4 * jj] * v.z + a[11 + 4 * jj] * v.w;
                    sp  += a[8 + 4 * jj] + a[9 + 4 * jj] +
                           a[10 + 4 * jj] + a[11 + 4 * jj];
                }
            }
        }
        // 4 output float4s: output d = 16qg+m at a[m+8]; tap t -> a[m+t+3]
        #pragma unroll
        for (int jj = 0; jj < 4; ++jj) {
            float s0 = 0.f, s1 = 0.f, s2 = 0.f, s3 = 0.f;
            #pragma unroll
            for (int t = 0; t < 11; ++t) {
                float g = GW[t];
                s0 += g * a[4 * jj + t + 3]; s1 += g * a[4 * jj + t + 4];
                s2 += g * a[4 * jj + t + 5]; s3 += g * a[4 * jj + t + 6];
            }
            tB[r * TBS + 4 * qg + jj] = make_float4(s0, s1, s2, s3);
        }
    }
    // block-reduce sums (same barrier covers tB completion + sm visibility)
    #pragma unroll
    for (int off = 32; off > 0; off >>= 1) {
        sip += __shfl_down(sip, off);
        sp  += __shfl_down(sp, off);
    }
    const int lane = threadIdx.x & 63;
    const int wid  = threadIdx.x >> 6;
    if (lane == 0) { sm[wid * 2] = sip; sm[wid * 2 + 1] = sp; }
    __syncthreads();
    if (threadIdx.x == 0)
        g_part1[tile] = make_float2(sm[0] + sm[2] + sm[4] + sm[6],
                                    sm[1] + sm[3] + sm[5] + sm[7]);
    // w-conv (11-tap LDS gather) + transposed bf16 ushort4 store
    ushort4* out4 = (ushort4*)g_bufT + ((size_t)c * VOL + (size_t)h * SIDE) / 4;
    for (int i = threadIdx.x; i < TW * Q; i += 256) {
        const int rl = i / Q, q = i - (i / Q) * Q;
        float sx = 0.f, sy = 0.f, sz = 0.f, sw = 0.f;
        #pragma unroll
        for (int t = 0; t < 11; ++t) {
            float g = GW[t];
            float4 v = tB[(rl + t) * TBS + q];
            sx += g * v.x; sy += g * v.y; sz += g * v.z; sw += g * v.w;
        }
        ushort4 o;
        o.x = f2bf(sx); o.y = f2bf(sy); o.z = f2bf(sz); o.w = f2bf(sw);
        out4[(size_t)(w0 + rl) * (SLAB / 4) + q] = o;
    }
}

// K2 (R14 winner, verbatim): block = (c, w, h-half). Stage the contiguous
// g_bufT[c][w][hh0-5..hh0+44][:] chunk (8 KB) into LDS as f32 ONCE
// (coalesced, 1.25x halo vs per-thread 3.5x window redundancy;
// bf16 cvt amortized to staging), h-conv from LDS, fused weights + dot.
// 1280 blocks = 5/CU exact; LDS 16.8 KB -> residency not limiting.
// IDEMPOTENT — R18 launches it 3x as a timing probe.
__global__ void __launch_bounds__(256) convh_dot_kernel(
        const float* __restrict__ labels, const float* __restrict__ img) {
    const int c   = blockIdx.x / CPB;
    const int rw  = blockIdx.x % CPB;
    const int w   = rw >> 1;
    const int hh0 = (rw & 1) * 40;
    const int n   = c >> 2;

    __shared__ float sB[50 * SBS];   // f32 window rows hh0-5..hh0+44
    __shared__ float sm[8];
    const int lane = threadIdx.x & 63;
    const int wid  = threadIdx.x >> 6;

    // oldest loads: mean partials (1 per thread, C1=160)
    float a = 0.f, b = 0.f;
    if (threadIdx.x < C1) {
        float2 p = g_part1[c * C1 + threadIdx.x];
        a = p.x; b = p.y;
    }

    // stage: contiguous bf16 chunk -> f32 LDS rows (zero-pad OOB halo)
    const ushort4* src = (const ushort4*)g_bufT + ((size_t)c * VOL + (size_t)w * SLAB) / 4;
    for (int i = threadIdx.x; i < 50 * Q; i += 256) {
        const int row = i / Q, s = i - (i / Q) * Q;
        const int hh = hh0 - RAD + row;
        float4 v = make_float4(0.f, 0.f, 0.f, 0.f);
        if ((unsigned)hh < SIDE) {
            ushort4 u = src[hh * Q + s];
            v = make_float4(bf2f(u.x), bf2f(u.y), bf2f(u.z), bf2f(u.w));
        }
        *(float4*)&sB[row * SBS + s * 4] = v;
    }

    // mean reduce (only needs the g_part1 loads)
    #pragma unroll
    for (int off = 32; off > 0; off >>= 1) {
        a += __shfl_down(a, off);
        b += __shfl_down(b, off);
    }
    if (lane == 0) { sm[wid * 2] = a; sm[wid * 2 + 1] = b; }
    __syncthreads();   // covers sB staging + sm visibility
    const float mean = (sm[0] + sm[2] + sm[4] + sm[6]) /
                       (sm[1] + sm[3] + sm[5] + sm[7] + 5.12f);   // VOL*EPS_MEAN

    // h-conv from LDS + fused weights + dot.  800 items = (40 h) x (20 q)
    const float4* labp4 = (const float4*)labels + (size_t)c * (VOL / 4);
    const float4* imgp4 = (const float4*)img + (size_t)n * (VOL / 4);
    float num = 0.f, den = 0.f;
    for (int i = threadIdx.x; i < TW * Q; i += 256) {
        const int hl = i / Q, q = i - (i / Q) * Q;
        const int h  = hh0 + hl;
        float sx = 0.f, sy = 0.f, sz = 0.f, sw = 0.f;
        #pragma unroll
        for (int t = 0; t < 11; ++t) {
            float g = GW[t];
            float4 v = *(const float4*)&sB[(hl + t) * SBS + q * 4];
            sx += g * v.x; sy += g * v.y; sz += g * v.z; sw += g * v.w;
        }
        const int li = h * (SLAB / 4) + w * Q + q;
        float4 l = labp4[li];
        float4 v = imgp4[li];
        float d0 = v.x - mean, d1 = v.y - mean, d2 = v.z - mean, d3 = v.w - mean;
        float q0 = d0 * d0, q1 = d1 * d1, q2 = d2 * d2, q3 = d3 * d3;
        float e0 = __expf(-q0 * q0), e1 = __expf(-q1 * q1);
        float e2 = __expf(-q2 * q2), e3 = __expf(-q3 * q3);
        num += sx * l.x * e0 + sy * l.y * e1 + sz * l.z * e2 + sw * l.w * e3;
        den += sx * e0 + sy * e1 + sz * e2 + sw * e3;
    }
    #pragma unroll
    for (int off = 32; off > 0; off >>= 1) {
        num += __shfl_down(num, off);
        den += __shfl_down(den, off);
    }
    __syncthreads();   // all threads done reading sm (mean) before reuse
    if (lane == 0) { sm[wid * 2] = num; sm[wid * 2 + 1] = den; }
    __syncthreads();
    if (threadIdx.x == 0)
        g_part2[blockIdx.x] = make_float2(sm[0] + sm[2] + sm[4] + sm[6],
                                          sm[1] + sm[3] + sm[5] + sm[7]);
}

// K3: reduce K2's per-block partials -> per-channel ratio -> loss scalar.
// Wave-parallel over channels (4 waves x 2 ch, 1 barrier). CPB=160.
__global__ void __launch_bounds__(256) final_kernel(float* __restrict__ out) {
    __shared__ float cn[NCH], cd[NCH];
    const int lane = threadIdx.x & 63;
    const int wid  = threadIdx.x >> 6;
    #pragma unroll
    for (int cc = 0; cc < 2; ++cc) {
        const int c = wid * 2 + cc;
        float a = 0.f, b = 0.f;
        for (int t = lane; t < CPB; t += 64) {
            float2 p = g_part2[c * CPB + t];
            a += p.x; b += p.y;
        }
        #pragma unroll
        for (int off = 32; off > 0; off >>= 1) {
            a += __shfl_down(a, off);
            b += __shfl_down(b, off);
        }
        if (lane == 0) { cn[c] = a; cd[c] = b; }
    }
    __syncthreads();
    if (threadIdx.x == 0) {
        float loss = 0.f;
        for (int k = 0; k < NCLS; ++k) {
            float r0 = cn[k]        / (cd[k]        + 1e-6f);
            float r1 = cn[NCLS + k] / (cd[NCLS + k] + 1e-6f);
            loss += 0.5f * (fabsf(r0) + fabsf(r1));   // mean over N=2, sum over K
        }
        out[0] = (float)NCLS - loss;
    }
}

extern "C" void kernel_launch(void* const* d_in, const int* in_sizes, int n_in,
                              void* d_out, int out_size, void* d_ws, size_t ws_size,
                              hipStream_t stream) {
    const float* labels = (const float*)d_in[0];   // (2,4,80,80,80) f32
    const float* img    = (const float*)d_in[1];   // (2,1,80,80,80) f32
    float* out = (float*)d_out;                    // 1 float
    (void)d_ws; (void)ws_size;                     // module-scope scratch

    // R18 MEASUREMENT ROUND: K2 launched 3x (idempotent -> output unchanged).
    // dur = 86.0 + 2*(K2+gap). Pre-committed reads:
    //   ~135-145 -> K2 25-28 µs, 3-4x over roofline -> R19 restructures K2;
    //   ~105-115 -> K2 10-14 µs, kernels near floor -> fill/overhead dominates;
    //   >=220    -> K2 ~70 µs pathological latency -> attack block structure.
    hipLaunchKernelGGL(convdw_sums_kernel, dim3(NBLK1), dim3(256), 0, stream, labels, img);
    hipLaunchKernelGGL(convh_dot_kernel,   dim3(NBLK2), dim3(256), 0, stream, labels, img);
    hipLaunchKernelGGL(convh_dot_kernel,   dim3(NBLK2), dim3(256), 0, stream, labels, img);
    hipLaunchKernelGGL(convh_dot_kernel,   dim3(NBLK2), dim3(256), 0, stream, labels, img);
    hipLaunchKernelGGL(final_kernel,       dim3(1),     dim3(256), 0, stream, out);
}

// Round 10
// 85.371 us; speedup vs baseline: 1.3056x; 1.2265x over previous
//
#include <hip/hip_runtime.h>
#include <math.h>

#define RAD 5
#define SIDE 80
#define SLAB 6400      // 80*80
#define VOL 512000     // 80^3
#define NCH 8          // N*K
#define NCLS 4
#define Q 20           // float4/ushort4 columns per 80-elem row
#define TW 40          // K1 tile extent along w (halo 1.25x; 1280 blocks = 5/CU resident)
#define NT 2           // w-tiles per axis (80/40)
#define C1 (SIDE*NT)           // 160 K1 slots per channel
#define NBLK1 (NCH*C1)         // 1280 K1 blocks
#define TBS 22                 // tB row stride in float4
#define NBLK2 1280             // K2 blocks: (c, w, h-half) = 8*80*2, 5/CU exact
#define CPB 160                // K2 blocks per channel
#define SBS 84                 // K2 LDS row stride in floats (21 float4, 336 B)

// exp(-t^2/32) for t=-5..5 (unnormalized Gaussian, symmetric)
__constant__ float GW[11] = {
    0.45783336177161427f, 0.6065306597126334f, 0.7548396019890073f,
    0.8824969025845955f,  0.969233234476344f,  1.0f,
    0.969233234476344f,   0.8824969025845955f, 0.7548396019890073f,
    0.6065306597126334f,  0.45783336177161427f};

// Module-scope scratch. Slot-based cross-kernel dataflow ONLY.
// R8/R16 (twice-measured): device atomics/fences cost tens of µs at 1000+
// block scale — kernel boundaries are the ONLY sync. R12: keep LDS <= ~17 KB
// for 5 blocks/CU residency. R17/R18 measured: K1+gap=10.5, K2+gap=9.3 µs;
// ~63 µs of the span is harness-fixed (d_ws poison fill + graph overhead).
__device__ unsigned short g_bufT[(size_t)NCH * VOL];  // bf16 conv'd labels, [c][w][h][d]
__device__ float2 g_part1[NBLK1];             // {S_ip, S_p} per K1 block
__device__ float2 g_part2[NBLK2];             // {num, den} per K2 block

__device__ __forceinline__ unsigned short f2bf(float f) {
    unsigned u = __float_as_uint(f);
    u += 0x7FFFu + ((u >> 16) & 1u);          // round-to-nearest-even
    return (unsigned short)(u >> 16);
}
__device__ __forceinline__ float bf2f(unsigned short h) {
    return __uint_as_float((unsigned)h << 16);
}

// K1: per (c, h, w-tile40): d-conv via register window from global,
// fused channel sums, w-conv via LDS gather, transposed bf16 store to g_bufT.
// R19 phase B: paired outputs — 2 adjacent w-rows share 10/11 taps, so one
// item reads 12 taps for 2 outputs (6 ds_read_b128/output vs 11). LDS-read
// time was the largest modeled component (~3.4 µs/CU at 11 taps/item).
__global__ void __launch_bounds__(256) convdw_sums_kernel(
        const float* __restrict__ labels, const float* __restrict__ img) {
    const int tile = blockIdx.x;
    const int c   = tile / C1;
    const int rem = tile % C1;
    const int h   = rem / NT;
    const int w0  = (rem % NT) * TW;
    const int n   = c >> 2;

    __shared__ float4 tB[(TW + 10) * TBS];   // d-conv result rows w0-5..w0+TW+4
    __shared__ float sm[8];

    const float4* labc4 = (const float4*)(labels + ((size_t)c * SIDE + h) * SLAB);
    const float4* imgc4 = (const float4*)(img + ((size_t)n * SIDE + h) * SLAB);

    float sip = 0.f, sp = 0.f;
    if (threadIdx.x < 250) {                 // 50 rows x 5 d-groups, 1 item/thread
        const int r  = threadIdx.x / 5;      // staged row 0..49
        const int qg = threadIdx.x % 5;      // 16-output d-group 0..4
        const int w  = w0 - RAD + r;
        float a[32];                         // labels at d = 16qg-8 .. 16qg+23
        #pragma unroll
        for (int j = 0; j < 32; ++j) a[j] = 0.f;
        if ((unsigned)w < SIDE) {
            const float4* row = labc4 + (size_t)w * Q;
            #pragma unroll
            for (int j = 0; j < 8; ++j) {
                int ss = 4 * qg - 2 + j;
                if (ss >= 0 && ss < Q) {
                    float4 v = row[ss];
                    a[4 * j] = v.x; a[4 * j + 1] = v.y;
                    a[4 * j + 2] = v.z; a[4 * j + 3] = v.w;
                }
            }
            if (r >= RAD && r < RAD + TW) {  // central rows: fused channel sums
                #pragma unroll
                for (int jj = 0; jj < 4; ++jj) {
                    float4 v = imgc4[(size_t)w * Q + 4 * qg + jj];
                    sip += a[8 + 4 * jj] * v.x + a[9 + 4 * jj] * v.y +
                           a[10 + 4 * jj] * v.z + a[11 + 4 * jj] * v.w;
                    sp  += a[8 + 4 * jj] + a[9 + 4 * jj] +
                           a[10 + 4 * jj] + a[11 + 4 * jj];
                }
            }
        }
        // 4 output float4s: output d = 16qg+m at a[m+8]; tap t -> a[m+t+3]
        #pragma unroll
        for (int jj = 0; jj < 4; ++jj) {
            float s0 = 0.f, s1 = 0.f, s2 = 0.f, s3 = 0.f;
            #pragma unroll
            for (int t = 0; t < 11; ++t) {
                float g = GW[t];
                s0 += g * a[4 * jj + t + 3]; s1 += g * a[4 * jj + t + 4];
                s2 += g * a[4 * jj + t + 5]; s3 += g * a[4 * jj + t + 6];
            }
            tB[r * TBS + 4 * qg + jj] = make_float4(s0, s1, s2, s3);
        }
    }
    // block-reduce sums (same barrier covers tB completion + sm visibility)
    #pragma unroll
    for (int off = 32; off > 0; off >>= 1) {
        sip += __shfl_down(sip, off);
        sp  += __shfl_down(sp, off);
    }
    const int lane = threadIdx.x & 63;
    const int wid  = threadIdx.x >> 6;
    if (lane == 0) { sm[wid * 2] = sip; sm[wid * 2 + 1] = sp; }
    __syncthreads();
    if (threadIdx.x == 0)
        g_part1[tile] = make_float2(sm[0] + sm[2] + sm[4] + sm[6],
                                    sm[1] + sm[3] + sm[5] + sm[7]);
    // w-conv: paired rows (2 outputs / 12 taps) + transposed bf16 stores
    ushort4* out4 = (ushort4*)g_bufT + ((size_t)c * VOL + (size_t)h * SIDE) / 4;
    for (int i = threadIdx.x; i < (TW / 2) * Q; i += 256) {   // 400 items
        const int rp = i / Q, q = i - (i / Q) * Q;
        const int rl = rp * 2;
        float s0x = 0.f, s0y = 0.f, s0z = 0.f, s0w = 0.f;
        float s1x = 0.f, s1y = 0.f, s1z = 0.f, s1w = 0.f;
        #pragma unroll
        for (int t = 0; t < 12; ++t) {
            float4 v = tB[(rl + t) * TBS + q];
            if (t < 11) {
                float g = GW[t];
                s0x += g * v.x; s0y += g * v.y; s0z += g * v.z; s0w += g * v.w;
            }
            if (t > 0) {
                float g = GW[t - 1];
                s1x += g * v.x; s1y += g * v.y; s1z += g * v.z; s1w += g * v.w;
            }
        }
        ushort4 o0, o1;
        o0.x = f2bf(s0x); o0.y = f2bf(s0y); o0.z = f2bf(s0z); o0.w = f2bf(s0w);
        o1.x = f2bf(s1x); o1.y = f2bf(s1y); o1.z = f2bf(s1z); o1.w = f2bf(s1w);
        out4[(size_t)(w0 + rl) * (SLAB / 4) + q] = o0;
        out4[(size_t)(w0 + rl + 1) * (SLAB / 4) + q] = o1;
    }
}

// K2 (R14 structure): block = (c, w, h-half); stage contiguous bf16 chunk ->
// f32 LDS once; h-conv from LDS; fused weights + dot.
// R19 main loop: paired h outputs — 12 taps read for 2 outputs (was 11 for 1).
__global__ void __launch_bounds__(256) convh_dot_kernel(
        const float* __restrict__ labels, const float* __restrict__ img) {
    const int c   = blockIdx.x / CPB;
    const int rw  = blockIdx.x % CPB;
    const int w   = rw >> 1;
    const int hh0 = (rw & 1) * 40;
    const int n   = c >> 2;

    __shared__ float sB[50 * SBS];   // f32 window rows hh0-5..hh0+44
    __shared__ float sm[8];
    const int lane = threadIdx.x & 63;
    const int wid  = threadIdx.x >> 6;

    // oldest loads: mean partials (1 per thread, C1=160)
    float a = 0.f, b = 0.f;
    if (threadIdx.x < C1) {
        float2 p = g_part1[c * C1 + threadIdx.x];
        a = p.x; b = p.y;
    }

    // stage: contiguous bf16 chunk -> f32 LDS rows (zero-pad OOB halo)
    const ushort4* src = (const ushort4*)g_bufT + ((size_t)c * VOL + (size_t)w * SLAB) / 4;
    for (int i = threadIdx.x; i < 50 * Q; i += 256) {
        const int row = i / Q, s = i - (i / Q) * Q;
        const int hh = hh0 - RAD + row;
        float4 v = make_float4(0.f, 0.f, 0.f, 0.f);
        if ((unsigned)hh < SIDE) {
            ushort4 u = src[hh * Q + s];
            v = make_float4(bf2f(u.x), bf2f(u.y), bf2f(u.z), bf2f(u.w));
        }
        *(float4*)&sB[row * SBS + s * 4] = v;
    }

    // mean reduce (only needs the g_part1 loads)
    #pragma unroll
    for (int off = 32; off > 0; off >>= 1) {
        a += __shfl_down(a, off);
        b += __shfl_down(b, off);
    }
    if (lane == 0) { sm[wid * 2] = a; sm[wid * 2 + 1] = b; }
    __syncthreads();   // covers sB staging + sm visibility
    const float mean = (sm[0] + sm[2] + sm[4] + sm[6]) /
                       (sm[1] + sm[3] + sm[5] + sm[7] + 5.12f);   // VOL*EPS_MEAN

    // paired h-conv from LDS + fused weights + dot. 400 items = 20 h-pairs x 20 q
    const float4* labp4 = (const float4*)labels + (size_t)c * (VOL / 4);
    const float4* imgp4 = (const float4*)img + (size_t)n * (VOL / 4);
    float num = 0.f, den = 0.f;
    for (int i = threadIdx.x; i < (TW / 2) * Q; i += 256) {
        const int hp = i / Q, q = i - (i / Q) * Q;
        const int hl = hp * 2;
        float s0x = 0.f, s0y = 0.f, s0z = 0.f, s0w = 0.f;
        float s1x = 0.f, s1y = 0.f, s1z = 0.f, s1w = 0.f;
        #pragma unroll
        for (int t = 0; t < 12; ++t) {
            float4 v = *(const float4*)&sB[(hl + t) * SBS + q * 4];
            if (t < 11) {
                float g = GW[t];
                s0x += g * v.x; s0y += g * v.y; s0z += g * v.z; s0w += g * v.w;
            }
            if (t > 0) {
                float g = GW[t - 1];
                s1x += g * v.x; s1y += g * v.y; s1z += g * v.z; s1w += g * v.w;
            }
        }
        #pragma unroll
        for (int k = 0; k < 2; ++k) {
            const float sx = k ? s1x : s0x, sy = k ? s1y : s0y;
            const float sz = k ? s1z : s0z, sw = k ? s1w : s0w;
            const int li = (hh0 + hl + k) * (SLAB / 4) + w * Q + q;
            float4 l = labp4[li];
            float4 v = imgp4[li];
            float d0 = v.x - mean, d1 = v.y - mean, d2 = v.z - mean, d3 = v.w - mean;
            float q0 = d0 * d0, q1 = d1 * d1, q2 = d2 * d2, q3 = d3 * d3;
            float e0 = __expf(-q0 * q0), e1 = __expf(-q1 * q1);
            float e2 = __expf(-q2 * q2), e3 = __expf(-q3 * q3);
            num += sx * l.x * e0 + sy * l.y * e1 + sz * l.z * e2 + sw * l.w * e3;
            den += sx * e0 + sy * e1 + sz * e2 + sw * e3;
        }
    }
    #pragma unroll
    for (int off = 32; off > 0; off >>= 1) {
        num += __shfl_down(num, off);
        den += __shfl_down(den, off);
    }
    __syncthreads();   // all threads done reading sm (mean) before reuse
    if (lane == 0) { sm[wid * 2] = num; sm[wid * 2 + 1] = den; }
    __syncthreads();
    if (threadIdx.x == 0)
        g_part2[blockIdx.x] = make_float2(sm[0] + sm[2] + sm[4] + sm[6],
                                          sm[1] + sm[3] + sm[5] + sm[7]);
}

// K3: reduce K2's per-block partials -> per-channel ratio -> loss scalar.
// Wave-parallel over channels (4 waves x 2 ch, 1 barrier). CPB=160.
__global__ void __launch_bounds__(256) final_kernel(float* __restrict__ out) {
    __shared__ float cn[NCH], cd[NCH];
    const int lane = threadIdx.x & 63;
    const int wid  = threadIdx.x >> 6;
    #pragma unroll
    for (int cc = 0; cc < 2; ++cc) {
        const int c = wid * 2 + cc;
        float a = 0.f, b = 0.f;
        for (int t = lane; t < CPB; t += 64) {
            float2 p = g_part2[c * CPB + t];
            a += p.x; b += p.y;
        }
        #pragma unroll
        for (int off = 32; off > 0; off >>= 1) {
            a += __shfl_down(a, off);
            b += __shfl_down(b, off);
        }
        if (lane == 0) { cn[c] = a; cd[c] = b; }
    }
    __syncthreads();
    if (threadIdx.x == 0) {
        float loss = 0.f;
        for (int k = 0; k < NCLS; ++k) {
            float r0 = cn[k]        / (cd[k]        + 1e-6f);
            float r1 = cn[NCLS + k] / (cd[NCLS + k] + 1e-6f);
            loss += 0.5f * (fabsf(r0) + fabsf(r1));   // mean over N=2, sum over K
        }
        out[0] = (float)NCLS - loss;
    }
}

extern "C" void kernel_launch(void* const* d_in, const int* in_sizes, int n_in,
                              void* d_out, int out_size, void* d_ws, size_t ws_size,
                              hipStream_t stream) {
    const float* labels = (const float*)d_in[0];   // (2,4,80,80,80) f32
    const float* img    = (const float*)d_in[1];   // (2,1,80,80,80) f32
    float* out = (float*)d_out;                    // 1 float
    (void)d_ws; (void)ws_size;                     // module-scope scratch

    hipLaunchKernelGGL(convdw_sums_kernel, dim3(NBLK1), dim3(256), 0, stream, labels, img);
    hipLaunchKernelGGL(convh_dot_kernel,   dim3(NBLK2), dim3(256), 0, stream, labels, img);
    hipLaunchKernelGGL(final_kernel,       dim3(1),     dim3(256), 0, stream, out);
}